// Round 17
// baseline (113.849 us; speedup 1.0000x reference)
//
#include <hip/hip_runtime.h>
#include <hip/hip_bf16.h>
#include <stdint.h>

// Problem constants
#define NB    32    // batch
#define CIN   128
#define HH    56
#define WW    56
#define COUT  256

// ws layout: wpack only (bf16, 36*8192 = 294,912 elems)
typedef __attribute__((ext_vector_type(4))) float f32x4;
typedef __attribute__((ext_vector_type(8))) short bf16x8;

__device__ __forceinline__ unsigned short f2bf(float f) {
    union { float f; unsigned u; } v; v.f = f;
    unsigned r = v.u + 0x7FFFu + ((v.u >> 16) & 1u);
    return (unsigned short)(r >> 16);
}

// ---------------------------------------------------------------------------
// build_weight: compose per-output-channel filters.
// wpack layout (R13-verified): [tile(36)][wid(4)][mf(4)][lane(64)][kin(8)]
//   elem = tile*8192 + wid*2048 + mf*512 + lane*8 + kin; tile = pos*4+cib,
//   o = wid*64+mf*16+fl, lane = kpos*16+fl, ci = cib*32+kpos*8+kin.
// ---------------------------------------------------------------------------
__global__ __launch_bounds__(256) void build_weight(
    const float* __restrict__ dict, const float* __restrict__ coef,
    const int* __restrict__ idxw, unsigned short* __restrict__ wpack) {
    int o = blockIdx.x;
    int tid = threadIdx.x;
    bool mode64 = (idxw[1] == 0) && (idxw[3] == 0) && (idxw[5] == 0) &&
                  (idxw[7] == 0) && (idxw[9] == 0) && (idxw[11] == 0) &&
                  (idxw[13] == 0) && (idxw[15] == 0);
    float c[8]; int di[8];
#pragma unroll
    for (int s = 0; s < 8; ++s) {
        c[s]  = coef[o * 8 + s];
        di[s] = mode64 ? idxw[(o * 8 + s) * 2] : idxw[o * 8 + s];
    }
    const int wid = o >> 6, mf = (o >> 4) & 3, fl = o & 15;
    for (int j = tid; j < 9 * 128; j += 256) {
        int pos = j >> 7;          // 0..8
        int ci  = j & 127;
        int kh = pos / 3, kw = pos - kh * 3;
        float v = 0.f;
#pragma unroll
        for (int s = 0; s < 8; ++s)
            v += c[s] * dict[((di[s] * CIN + ci) * 3 + kh) * 3 + kw];
        int tile = pos * 4 + (ci >> 5);
        int kpos = (ci >> 3) & 3, kin = ci & 7;
        wpack[tile * 8192 + wid * 2048 + mf * 512 + (kpos * 16 + fl) * 8 + kin]
            = f2bf(v);
    }
}

// ---------------------------------------------------------------------------
// Main: FUSED pack + implicit-GEMM conv (R17 = R16 with the bank-conflict
// fix). R16 post-mortem: 4.13M LDS conflicts, two causes:
//  (a) ch-stride 520 broke the verified stride-512 READ pattern
//      (at 512 elems = 256 dwords, bank = f(iw) only -> BW-floor reads);
//  (b) pack mapped lanes to ci, so each b32 write had ONE w across the
//      wave -> 4 banks -> 16-way write conflict.
// Fix: stride back to 512 (main loop = R15 verbatim, measured 67us/0 confl)
// and pack remapped LANE = IW: coalesced 4B x-loads (w varies across
// lanes), pack bf16x8 in regs, ONE 16B slab write per (row,ch) -> lanes
// uniform over iw mod 8 = bandwidth-floor writes.
//  - slab [row(3)][ch(16)][iw(64)][kin(8)], elem stride 512/ch.
//  - pad lanes (iw=0,57..63; h=-1,56) write zeros via select, clamped addrs.
//  - (256,3), LDS 49.4 KB -> 3 blocks/CU; regs ~80 arch + 64 AGPR (R15).
// ---------------------------------------------------------------------------
__global__ __launch_bounds__(256, 3) void conv_mfma(
    const float* __restrict__ x,
    const unsigned short* __restrict__ wpack,
    float* __restrict__ out) {
    // slab: elem = (row*16 + ch)*512 + iw*8 + kin ; +128 pad (junk-col reads)
    __shared__ unsigned short Bl[3 * 16 * 512 + 128];

    int tid  = threadIdx.x;
    int lane = tid & 63;
    int wid  = tid >> 6;       // 0..3 = Cout slice of 64 (and ci-quarter in pack)

    // XCD-bijective swizzle: 1792 = 8 * 224; each XCD gets 4 consecutive b's
    int flat = blockIdx.x;
    int swz  = (flat & 7) * 224 + (flat >> 3);
    int b    = swz / 56;       // 0..31
    int oh   = swz % 56;       // output row

    const int klane = lane >> 4;   // k-group (0..3)
    const int fl    = lane & 15;

    // A-fragment base (coalesced): af(tile,mf) = ap0 + tile*8192 + mf*512 elems
    const unsigned short* ap0 = wpack + (size_t)wid * 2048 + lane * 8;

    // ---- issue A(tile 0) early: latency hides under the pack phase ----
    bf16x8 af[2][4];
#pragma unroll
    for (int mf = 0; mf < 4; ++mf)
        af[0][mf] = *(const bf16x8*)(ap0 + mf * 512);

    // ---- fused pack: lane = iw; wid = ci-quarter (8 ci per ch, 4 ch) ----
    {
        const int iw = lane;
        const bool valid_w = (iw >= 1) && (iw <= WW);
        const int w = valid_w ? iw - 1 : 0;
#pragma unroll
        for (int row = 0; row < 3; ++row) {
            int h = oh + row - 1;
            bool valid = valid_w && (h >= 0) && (h < HH);
            int hc = h < 0 ? 0 : (h > HH - 1 ? HH - 1 : h);
            const float* px =
                x + (((size_t)b * CIN + wid * 32) * HH + hc) * WW + w;
#pragma unroll
            for (int c = 0; c < 4; ++c) {
                int ch = wid * 4 + c;
                bf16x8 pv;
#pragma unroll
                for (int j = 0; j < 8; ++j) {
                    float v = px[(size_t)(c * 8 + j) * (HH * WW)];
                    pv[j] = valid ? (short)f2bf(v) : (short)0;
                }
                *(bf16x8*)&Bl[(row * 16 + ch) * 512 + iw * 8] = pv;
            }
        }
    }

    f32x4 acc[4][4];
    f32x4 zero = {0.f, 0.f, 0.f, 0.f};
#pragma unroll
    for (int i = 0; i < 4; ++i)
#pragma unroll
        for (int j = 0; j < 4; ++j) acc[i][j] = zero;

    __syncthreads();   // slab resident; ONLY barrier in the kernel

    const unsigned short* apc = ap0;                       // += 8192/cib
    const unsigned short* bl0 = &Bl[klane * 512 + fl * 8];

#pragma unroll 2
    for (int cib = 0; cib < 4; ++cib) {
        const unsigned short* bcur = bl0 + cib * 2048;     // 4 ch per cib

#pragma unroll
        for (int pos = 0; pos < 9; ++pos) {
            const int kh = pos / 3, kw = pos - kh * 3;
            const int cur = (cib + pos) & 1;   // STATIC under unroll-2 cib

            // ---- prefetch A(next step) into the free set (ping-pong) ----
            if (pos < 8) {
#pragma unroll
                for (int mf = 0; mf < 4; ++mf)
                    af[cur ^ 1][mf] =
                        *(const bf16x8*)(apc + (pos + 1) * 32768 + mf * 512);
            } else if (cib < 3) {
#pragma unroll
                for (int mf = 0; mf < 4; ++mf)
                    af[cur ^ 1][mf] = *(const bf16x8*)(apc + 8192 + mf * 512);
            }

            // ---- B fragments from resident slab (imm-offset ds_read) ----
            bf16x8 bfr[4];
#pragma unroll
            for (int nf = 0; nf < 4; ++nf)
                bfr[nf] = *(const bf16x8*)(bcur + kh * 8192 + (nf * 16 + kw) * 8);

            // ---- 16 MFMA on af[cur] (loaded a full step ago) ----
            __builtin_amdgcn_s_setprio(1);
#pragma unroll
            for (int mf = 0; mf < 4; ++mf)
#pragma unroll
                for (int nf = 0; nf < 4; ++nf)
                    acc[mf][nf] = __builtin_amdgcn_mfma_f32_16x16x32_bf16(
                        af[cur][mf], bfr[nf], acc[mf][nf], 0, 0, 0);
            __builtin_amdgcn_s_setprio(0);
        }
        apc += 8192;
    }

    // Epilogue: C/D layout col = lane&15, row = (lane>>4)*4 + reg (m89-verified)
#pragma unroll
    for (int nf = 0; nf < 4; ++nf) {
        int ow = nf * 16 + fl;
        if (ow < WW) {
#pragma unroll
            for (int mf = 0; mf < 4; ++mf) {
                int ob = wid * 64 + mf * 16 + (lane >> 4) * 4;
                float* dst = out + (((size_t)b * COUT + ob) * HH + oh) * WW + ow;
#pragma unroll
                for (int r = 0; r < 4; ++r)
                    dst[(size_t)r * HH * WW] = acc[mf][nf][r];
            }
        }
    }
}

extern "C" void kernel_launch(void* const* d_in, const int* in_sizes, int n_in,
                              void* d_out, int out_size, void* d_ws, size_t ws_size,
                              hipStream_t stream) {
    const float* x    = (const float*)d_in[0];
    const float* dict = (const float*)d_in[1];
    const float* coef = (const float*)d_in[2];
    const int*   idxw = (const int*)d_in[3];
    float* out = (float*)d_out;

    unsigned short* wpack = (unsigned short*)d_ws;

    build_weight<<<dim3(COUT), dim3(256), 0, stream>>>(dict, coef, idxw, wpack);
    conv_mfma<<<dim3(NB * 56), dim3(256), 0, stream>>>(x, wpack, out);
}

// Round 18
// 88.616 us; speedup vs baseline: 1.2847x; 1.2847x over previous
//
#include <hip/hip_runtime.h>
#include <hip/hip_bf16.h>
#include <stdint.h>

// Problem constants
#define NB    32    // batch
#define CIN   128
#define HH    56
#define WW    56
#define COUT  256
#define HP    58    // padded height (H+2)
#define WP    64    // padded width (56+2 -> padded to 64)

// ws layout: xp (bf16, NB*HP*WP*CIN) then wpack (bf16, 36*8192)
#define XP_ELEMS   (NB * HP * WP * CIN)

typedef __attribute__((ext_vector_type(4))) float f32x4;
typedef __attribute__((ext_vector_type(8))) short bf16x8;

__device__ __forceinline__ unsigned short f2bf(float f) {
    union { float f; unsigned u; } v; v.f = f;
    unsigned r = v.u + 0x7FFFu + ((v.u >> 16) & 1u);
    return (unsigned short)(r >> 16);
}

__device__ __forceinline__ void gload16(const void* g, void* l) {
    __builtin_amdgcn_global_load_lds(
        (__attribute__((address_space(1))) void*)(void*)g,
        (__attribute__((address_space(3))) void*)l,
        16, 0, 0);
}

// ---------------------------------------------------------------------------
// Fused prep (R15-verified): blocks [0,256) compose weights; the rest pack x.
// wpack layout (R13-verified): [tile(36)][wid(4)][mf(4)][lane(64)][kin(8)]
// xp layout (R14-verified):    [b][ih][ch(16)][iw(64)][kin(8)]
// ---------------------------------------------------------------------------
__global__ __launch_bounds__(256) void prep(
    const float* __restrict__ x, const float* __restrict__ dict,
    const float* __restrict__ coef, const int* __restrict__ idxw,
    unsigned short* __restrict__ wpack, unsigned short* __restrict__ xp) {
    int tid = threadIdx.x;

    if (blockIdx.x < COUT) {
        // ---- build_weight ----
        int o = blockIdx.x;
        bool mode64 = (idxw[1] == 0) && (idxw[3] == 0) && (idxw[5] == 0) &&
                      (idxw[7] == 0) && (idxw[9] == 0) && (idxw[11] == 0) &&
                      (idxw[13] == 0) && (idxw[15] == 0);
        float c[8]; int di[8];
#pragma unroll
        for (int s = 0; s < 8; ++s) {
            c[s]  = coef[o * 8 + s];
            di[s] = mode64 ? idxw[(o * 8 + s) * 2] : idxw[o * 8 + s];
        }
        const int wid = o >> 6, mf = (o >> 4) & 3, fl = o & 15;
        for (int j = tid; j < 9 * 128; j += 256) {
            int pos = j >> 7;          // 0..8
            int ci  = j & 127;
            int kh = pos / 3, kw = pos - kh * 3;
            float v = 0.f;
#pragma unroll
            for (int s = 0; s < 8; ++s)
                v += c[s] * dict[((di[s] * CIN + ci) * 3 + kh) * 3 + kw];
            int tile = pos * 4 + (ci >> 5);
            int kpos = (ci >> 3) & 3, kin = ci & 7;
            wpack[tile * 8192 + wid * 2048 + mf * 512 + (kpos * 16 + fl) * 8 + kin]
                = f2bf(v);
        }
        return;
    }

    // ---- pack_x: NCHW fp32 -> zero-padded [ch][iw][kin] bf16 ----
    int idx = blockIdx.x - COUT;
    int ih = idx % HP;         // 0..57
    int b  = idx / HP;         // 0..31
    size_t obase = ((size_t)(b * HP + ih)) * WP * CIN;
    bf16x8* outv = (bf16x8*)(xp + obase);   // 1024 vectors: index = ch*64 + iw

    if (ih == 0 || ih == HP - 1) {
        bf16x8 z = {0, 0, 0, 0, 0, 0, 0, 0};
        for (int e = tid; e < WP * CIN / 8; e += 256) outv[e] = z;
        return;
    }

    __shared__ float xs[CIN][WW + 1];   // +1 pad: odd stride
    int h = ih - 1;
    for (int e = tid; e < CIN * WW; e += 256) {
        int ci = e / WW, w = e - ci * WW;
        xs[ci][w] = x[(((size_t)b * CIN + ci) * HH + h) * WW + w];
    }
    __syncthreads();
    for (int e = tid; e < WP * CIN / 8; e += 256) {
        int iw = e & 63;             // fast-varying -> coalesced stores
        int cb = (e >> 6) << 3;      // ci base
        bf16x8 v = {0, 0, 0, 0, 0, 0, 0, 0};
        if (iw >= 1 && iw <= WW) {
#pragma unroll
            for (int j = 0; j < 8; ++j)
                v[j] = (short)f2bf(xs[cb + j][iw - 1]);
        }
        outv[e] = v;
    }
}

// ---------------------------------------------------------------------------
// Main: implicit-GEMM conv, RESIDENT-B slab + R18: 8-wave blocks for
// 4 waves/SIMD.  R17 post-mortem: fused pack fails twice (conflicts /
// serialized scalar loads) -> back to the split structure (conv 66.6us).
// The untried occupancy step: block = 512 threads = 8 waves = 256 Cout x
// TWO output rows. Wave (wm = wid&3, wr = wid>>2) keeps the VERIFIED
// per-wave shape (acc[4][4], 64 AGPR, ~80 VGPR). Slab = 4 rows = 64 KB;
// LDS pins exactly 2 blocks/CU -> 16 waves/CU = 4/SIMD (was 3/SIMD).
// __launch_bounds__(512,2) NOT (512,4): the latter caps 128 unified regs
// -> acc spills (R3/R5 lesson). wr-paired waves issue identical A-loads
// (L1 dedup) so A L2 traffic/CU is unchanged.
// Main loop byte-equivalent to R15's verified loop (ping-pong af,
// imm-offset ds_reads, stride 512, 0 bank conflicts).
// ---------------------------------------------------------------------------
__global__ __launch_bounds__(512, 2) void conv_mfma(
    const unsigned short* __restrict__ xp,
    const unsigned short* __restrict__ wpack,
    float* __restrict__ out) {
    // slab: elem = ((row*16 + ch)*512 + iw*8 + kin); rows 0..3; +128 junk pad
    __shared__ unsigned short Bl[4 * 16 * 512 + 128];

    int tid  = threadIdx.x;
    int lane = tid & 63;
    int wid  = tid >> 6;       // 0..7
    int wm   = wid & 3;        // Cout slice of 64
    int wr   = wid >> 2;       // output row within pair (0/1)

    // XCD-bijective swizzle: 896 = 8 * 112; each XCD gets 4 consecutive b's
    int flat = blockIdx.x;
    int swz  = (flat & 7) * 112 + (flat >> 3);
    int b    = swz / 28;       // 0..31
    int oh0  = (swz % 28) * 2; // rows oh0 (wr=0), oh0+1 (wr=1)

    const int klane = lane >> 4;   // k-group (0..3)
    const int fl    = lane & 15;

    f32x4 acc[4][4];
    f32x4 zero = {0.f, 0.f, 0.f, 0.f};
#pragma unroll
    for (int i = 0; i < 4; ++i)
#pragma unroll
        for (int j = 0; j < 4; ++j) acc[i][j] = zero;

    // A-fragment base (coalesced): af(tile,mf) = ap0 + tile*8192 + mf*512 elems
    const unsigned short* ap0 = wpack + (size_t)wm * 2048 + lane * 8;

    // ---- prologue: stage 4-row slab (64 slices of 1 KB, linear copy) ----
    const unsigned short* xrow = xp + ((size_t)(b * HP + oh0)) * 8192;
#pragma unroll
    for (int j = 0; j < 8; ++j) {
        int s = wid + j * 8;           // 0..63 = row*16 + ch
        gload16(xrow + (size_t)(s >> 4) * 8192 + (s & 15) * 512 + lane * 8,
                &Bl[s * 512]);
    }

    bf16x8 af[2][4];
#pragma unroll
    for (int mf = 0; mf < 4; ++mf)
        af[0][mf] = *(const bf16x8*)(ap0 + mf * 512);
    __syncthreads();   // slab resident; ONLY barrier in the kernel

    const unsigned short* apc = ap0;                       // += 8192/cib
    const unsigned short* bl0 = &Bl[(wr * 16 + klane) * 512 + fl * 8];

#pragma unroll 2
    for (int cib = 0; cib < 4; ++cib) {
        const unsigned short* bcur = bl0 + cib * 2048;     // 4 ch per cib

#pragma unroll
        for (int pos = 0; pos < 9; ++pos) {
            const int kh = pos / 3, kw = pos - kh * 3;
            const int cur = (cib + pos) & 1;   // STATIC under unroll-2 cib

            // ---- prefetch A(next step) into the free set (ping-pong) ----
            if (pos < 8) {
#pragma unroll
                for (int mf = 0; mf < 4; ++mf)
                    af[cur ^ 1][mf] =
                        *(const bf16x8*)(apc + (pos + 1) * 32768 + mf * 512);
            } else if (cib < 3) {
#pragma unroll
                for (int mf = 0; mf < 4; ++mf)
                    af[cur ^ 1][mf] = *(const bf16x8*)(apc + 8192 + mf * 512);
            }

            // ---- B fragments from resident slab (imm-offset ds_read) ----
            bf16x8 bfr[4];
#pragma unroll
            for (int nf = 0; nf < 4; ++nf)
                bfr[nf] = *(const bf16x8*)(bcur + kh * 8192 + (nf * 16 + kw) * 8);

            // ---- 16 MFMA on af[cur] (loaded a full step ago) ----
            __builtin_amdgcn_s_setprio(1);
#pragma unroll
            for (int mf = 0; mf < 4; ++mf)
#pragma unroll
                for (int nf = 0; nf < 4; ++nf)
                    acc[mf][nf] = __builtin_amdgcn_mfma_f32_16x16x32_bf16(
                        af[cur][mf], bfr[nf], acc[mf][nf], 0, 0, 0);
            __builtin_amdgcn_s_setprio(0);
        }
        apc += 8192;
    }

    // Epilogue: C/D layout col = lane&15, row = (lane>>4)*4 + reg (m89-verified)
    int oh = oh0 + wr;
#pragma unroll
    for (int nf = 0; nf < 4; ++nf) {
        int ow = nf * 16 + fl;
        if (ow < WW) {
#pragma unroll
            for (int mf = 0; mf < 4; ++mf) {
                int ob = wm * 64 + mf * 16 + (lane >> 4) * 4;
                float* dst = out + (((size_t)b * COUT + ob) * HH + oh) * WW + ow;
#pragma unroll
                for (int r = 0; r < 4; ++r)
                    dst[(size_t)r * HH * WW] = acc[mf][nf][r];
            }
        }
    }
}

extern "C" void kernel_launch(void* const* d_in, const int* in_sizes, int n_in,
                              void* d_out, int out_size, void* d_ws, size_t ws_size,
                              hipStream_t stream) {
    const float* x    = (const float*)d_in[0];
    const float* dict = (const float*)d_in[1];
    const float* coef = (const float*)d_in[2];
    const int*   idxw = (const int*)d_in[3];
    float* out = (float*)d_out;

    unsigned short* xp    = (unsigned short*)d_ws;
    unsigned short* wpack = xp + XP_ELEMS;

    prep<<<dim3(COUT + HP * NB), dim3(256), 0, stream>>>(x, dict, coef, idxw, wpack, xp);
    conv_mfma<<<dim3(28 * NB), dim3(512), 0, stream>>>(xp, wpack, out);
}

// Round 19
// 78.281 us; speedup vs baseline: 1.4544x; 1.1320x over previous
//
#include <hip/hip_runtime.h>
#include <hip/hip_bf16.h>
#include <stdint.h>

// Problem constants
#define NB    32    // batch
#define CIN   128
#define HH    56
#define WW    56
#define COUT  256

// ws layout: wpack only (bf16, 36*8192 = 294,912 elems)
typedef __attribute__((ext_vector_type(4))) float f32x4;
typedef __attribute__((ext_vector_type(8))) short bf16x8;

__device__ __forceinline__ unsigned short f2bf(float f) {
    union { float f; unsigned u; } v; v.f = f;
    unsigned r = v.u + 0x7FFFu + ((v.u >> 16) & 1u);
    return (unsigned short)(r >> 16);
}

// ---------------------------------------------------------------------------
// build_weight: compose per-output-channel filters.
// wpack layout (R13-verified): [tile(36)][wid(4)][mf(4)][lane(64)][kin(8)]
//   elem = tile*8192 + wid*2048 + mf*512 + lane*8 + kin; tile = pos*4+cib,
//   o = wid*64+mf*16+fl, lane = kpos*16+fl, ci = cib*32+kpos*8+kin.
// ---------------------------------------------------------------------------
__global__ __launch_bounds__(256) void build_weight(
    const float* __restrict__ dict, const float* __restrict__ coef,
    const int* __restrict__ idxw, unsigned short* __restrict__ wpack) {
    int o = blockIdx.x;
    int tid = threadIdx.x;
    bool mode64 = (idxw[1] == 0) && (idxw[3] == 0) && (idxw[5] == 0) &&
                  (idxw[7] == 0) && (idxw[9] == 0) && (idxw[11] == 0) &&
                  (idxw[13] == 0) && (idxw[15] == 0);
    float c[8]; int di[8];
#pragma unroll
    for (int s = 0; s < 8; ++s) {
        c[s]  = coef[o * 8 + s];
        di[s] = mode64 ? idxw[(o * 8 + s) * 2] : idxw[o * 8 + s];
    }
    const int wid = o >> 6, mf = (o >> 4) & 3, fl = o & 15;
    for (int j = tid; j < 9 * 128; j += 256) {
        int pos = j >> 7;          // 0..8
        int ci  = j & 127;
        int kh = pos / 3, kw = pos - kh * 3;
        float v = 0.f;
#pragma unroll
        for (int s = 0; s < 8; ++s)
            v += c[s] * dict[((di[s] * CIN + ci) * 3 + kh) * 3 + kw];
        int tile = pos * 4 + (ci >> 5);
        int kpos = (ci >> 3) & 3, kin = ci & 7;
        wpack[tile * 8192 + wid * 2048 + mf * 512 + (kpos * 16 + fl) * 8 + kin]
            = f2bf(v);
    }
}

// ---------------------------------------------------------------------------
// Main: FUSED pack + implicit-GEMM conv (R19 = fusion with BOTH prior
// failures fixed):
//  - R16 failure: stride-520 slab broke the verified stride-512 READ
//    pattern (4.1M conflicts). -> stride 512, main loop = R15 verbatim.
//  - R17 failure: pack loads serialized (per-element load->cvt->write
//    chains, ~30k cyc/block). -> BATCHED loads: 32 independent floats
//    into a register array per row, ONE implicit wait, then 4 bf16x8
//    converts + conflict-free 16B/lane writes (lane = iw mapping, same
//    linear pattern as gload16; R17 measured 0 conflicts on this).
//  - Pack thread map: wave q (0..3) owns ci q*32..q*32+31; lane = iw.
//    Loads coalesced across lanes (w contiguous); pad lanes (iw=0,57..63)
//    and pad rows (h=-1,56) select 0 via clamped addresses.
//  - A(tile 0) issued BEFORE pack -> L2 latency hidden under pack.
//  - (256,3): 3 blocks/CU by LDS (49.7 KB); ~90 arch + 64 AGPR unified
//    = ~154 <= 170 (R18 lesson: unified regs x waves/SIMD <= 512).
// ---------------------------------------------------------------------------
__global__ __launch_bounds__(256, 3) void conv_mfma(
    const float* __restrict__ x,
    const unsigned short* __restrict__ wpack,
    float* __restrict__ out) {
    // slab: elem = (row*16 + ch)*512 + iw*8 + kin ; +128 pad (junk-col reads)
    __shared__ unsigned short Bl[3 * 16 * 512 + 128];

    int tid  = threadIdx.x;
    int lane = tid & 63;
    int wid  = tid >> 6;       // 0..3 = Cout slice of 64 (and ci-quarter in pack)

    // XCD-bijective swizzle: 1792 = 8 * 224; each XCD gets 4 consecutive b's
    int flat = blockIdx.x;
    int swz  = (flat & 7) * 224 + (flat >> 3);
    int b    = swz / 56;       // 0..31
    int oh   = swz % 56;       // output row

    const int klane = lane >> 4;   // k-group (0..3)
    const int fl    = lane & 15;

    // A-fragment base (coalesced): af(tile,mf) = ap0 + tile*8192 + mf*512 elems
    const unsigned short* ap0 = wpack + (size_t)wid * 2048 + lane * 8;

    // ---- issue A(tile 0) early: latency hides under the pack phase ----
    bf16x8 af[2][4];
#pragma unroll
    for (int mf = 0; mf < 4; ++mf)
        af[0][mf] = *(const bf16x8*)(ap0 + mf * 512);

    // ---- fused pack: lane = iw, wave = ci-quarter; batched 32-float loads ----
    {
        const int iw = lane;
        const bool vw = (iw >= 1) && (iw <= WW);
        const int w = vw ? iw - 1 : 0;
#pragma unroll
        for (int row = 0; row < 3; ++row) {
            int h = oh + row - 1;
            bool valid = vw && (h >= 0) && (h < HH);
            int hc = h < 0 ? 0 : (h >= HH ? HH - 1 : h);
            const float* px =
                x + (((size_t)b * CIN + wid * 32) * HH + hc) * WW + w;
            float v[32];
#pragma unroll
            for (int j = 0; j < 32; ++j)          // 32 independent loads
                v[j] = px[(size_t)j * (HH * WW)];
#pragma unroll
            for (int c = 0; c < 4; ++c) {         // one wait, 4 vector writes
                bf16x8 pv;
#pragma unroll
                for (int j = 0; j < 8; ++j)
                    pv[j] = valid ? (short)f2bf(v[c * 8 + j]) : (short)0;
                *(bf16x8*)&Bl[(row * 16 + wid * 4 + c) * 512 + iw * 8] = pv;
            }
        }
    }

    f32x4 acc[4][4];
    f32x4 zero = {0.f, 0.f, 0.f, 0.f};
#pragma unroll
    for (int i = 0; i < 4; ++i)
#pragma unroll
        for (int j = 0; j < 4; ++j) acc[i][j] = zero;

    __syncthreads();   // slab resident; ONLY barrier in the kernel

    const unsigned short* apc = ap0;                       // += 8192/cib
    const unsigned short* bl0 = &Bl[klane * 512 + fl * 8];

#pragma unroll 2
    for (int cib = 0; cib < 4; ++cib) {
        const unsigned short* bcur = bl0 + cib * 2048;     // 4 ch per cib

#pragma unroll
        for (int pos = 0; pos < 9; ++pos) {
            const int kh = pos / 3, kw = pos - kh * 3;
            const int cur = (cib + pos) & 1;   // STATIC under unroll-2 cib

            // ---- prefetch A(next step) into the free set (ping-pong) ----
            if (pos < 8) {
#pragma unroll
                for (int mf = 0; mf < 4; ++mf)
                    af[cur ^ 1][mf] =
                        *(const bf16x8*)(apc + (pos + 1) * 32768 + mf * 512);
            } else if (cib < 3) {
#pragma unroll
                for (int mf = 0; mf < 4; ++mf)
                    af[cur ^ 1][mf] = *(const bf16x8*)(apc + 8192 + mf * 512);
            }

            // ---- B fragments from resident slab (imm-offset ds_read) ----
            bf16x8 bfr[4];
#pragma unroll
            for (int nf = 0; nf < 4; ++nf)
                bfr[nf] = *(const bf16x8*)(bcur + kh * 8192 + (nf * 16 + kw) * 8);

            // ---- 16 MFMA on af[cur] (loaded a full step ago) ----
            __builtin_amdgcn_s_setprio(1);
#pragma unroll
            for (int mf = 0; mf < 4; ++mf)
#pragma unroll
                for (int nf = 0; nf < 4; ++nf)
                    acc[mf][nf] = __builtin_amdgcn_mfma_f32_16x16x32_bf16(
                        af[cur][mf], bfr[nf], acc[mf][nf], 0, 0, 0);
            __builtin_amdgcn_s_setprio(0);
        }
        apc += 8192;
    }

    // Epilogue: C/D layout col = lane&15, row = (lane>>4)*4 + reg (m89-verified)
#pragma unroll
    for (int nf = 0; nf < 4; ++nf) {
        int ow = nf * 16 + fl;
        if (ow < WW) {
#pragma unroll
            for (int mf = 0; mf < 4; ++mf) {
                int ob = wid * 64 + mf * 16 + (lane >> 4) * 4;
                float* dst = out + (((size_t)b * COUT + ob) * HH + oh) * WW + ow;
#pragma unroll
                for (int r = 0; r < 4; ++r)
                    dst[(size_t)r * HH * WW] = acc[mf][nf][r];
            }
        }
    }
}

extern "C" void kernel_launch(void* const* d_in, const int* in_sizes, int n_in,
                              void* d_out, int out_size, void* d_ws, size_t ws_size,
                              hipStream_t stream) {
    const float* x    = (const float*)d_in[0];
    const float* dict = (const float*)d_in[1];
    const float* coef = (const float*)d_in[2];
    const int*   idxw = (const int*)d_in[3];
    float* out = (float*)d_out;

    unsigned short* wpack = (unsigned short*)d_ws;

    build_weight<<<dim3(COUT), dim3(256), 0, stream>>>(dict, coef, idxw, wpack);
    conv_mfma<<<dim3(NB * 56), dim3(256), 0, stream>>>(x, wpack, out);
}